// Round 13
// baseline (1472.848 us; speedup 1.0000x reference)
//
#include <hip/hip_runtime.h>

#define NB 256
#define BLK 1024
#define TSn 95
#define DYn 90
#define DPn 80
#define DINn 170
#define Hn 4096

typedef unsigned int uint32;
typedef unsigned long long uint64;
typedef _Float16 h2v __attribute__((ext_vector_type(2)));

// ---- ws byte offsets (layout identical to R10-R12, payloads f16x2) ----
#define B_W3T 0ull             // 4096x4096 f16 transposed rows (8KB/row)
#define B_MT  33554432ull      // M = (W1a^T W4^T), same layout
#define B_UPB 67108864ull      // 95 x 2048 u32 (f16x2)
#define B_C   67887104ull      // 4096 f32
#define B_H1X 67903488ull      // uint64[2048] tagged {f16x2 payload, epoch}
#define B_H2X 67919872ull
#define B_H3X 67936256ull
#define B_H3H 67952640ull      // 95 x 2048 u32 (plain f16x2 h3 history)
#define WS_NEED 68730880ull

// out float offsets
#define O_YU 0
#define O_YL 8640
#define O_P1 17280
#define O_PU 24960
#define O_PL 32640

__device__ __forceinline__ void st_tag(uint64* p, uint64 v) {
  __hip_atomic_store(p, v, __ATOMIC_RELAXED, __HIP_MEMORY_SCOPE_AGENT);
}
__device__ __forceinline__ uint32 pkh(float x, float y) {
  h2v h; h[0] = (_Float16)x; h[1] = (_Float16)y;
  return __builtin_bit_cast(uint32, h);
}
__device__ __forceinline__ float hlo(uint32 u) { h2v h = __builtin_bit_cast(h2v, u); return (float)h[0]; }
__device__ __forceinline__ float hhi(uint32 u) { h2v h = __builtin_bit_cast(h2v, u); return (float)h[1]; }
__device__ __forceinline__ float dot2(uint32 a, uint32 b, float c) {
  return __builtin_amdgcn_fdot2(__builtin_bit_cast(h2v, a), __builtin_bit_cast(h2v, b), c, false);
}
__device__ __forceinline__ float wred(float v) {
#pragma unroll
  for (int o = 32; o > 0; o >>= 1) v += __shfl_xor(v, o, 64);
  return v;
}
// 16B DEVICE-scope load (sc1 only): L2-bypassing, MALL-served, cross-XCD
// coherent — same scope the compiler emits for agent relaxed atomics.
// (R12's "sc0 sc1" was SYSTEM scope -> bypassed the MALL -> 3.3 GB of HBM.)
__device__ __forceinline__ uint4 ld16_dev(const uint64* p) {
  uint4 v;
  asm volatile("global_load_dwordx4 %0, %1, off sc1\n\ts_waitcnt vmcnt(0)"
               : "=v"(v) : "v"(p) : "memory");
  return v;
}

// ---------------- prologue kernels ----------------
// W3 f32 -> f16x2 transposed rows.
extern "C" __global__ __launch_bounds__(256)
void t3_kernel(const float* __restrict__ W3, uint32* __restrict__ W3T) {
  const int m = blockIdx.x;
  const int j0 = (m >> 6) * 64, k0 = (m & 63) * 64;
  const int t = threadIdx.x;
  __shared__ float lds[64][65];
  const int jl = t & 63, kb = t >> 6;
#pragma unroll
  for (int i = 0; i < 16; ++i) {
    const int kl = kb + 4 * i;
    lds[kl][jl] = W3[(size_t)(k0 + kl) * Hn + j0 + jl];
  }
  __syncthreads();
  const int kp = t & 31, jb = t >> 5;
#pragma unroll
  for (int i = 0; i < 8; ++i) {
    const int jr = jb + 8 * i;
    W3T[(size_t)(j0 + jr) * 2048 + (k0 >> 1) + kp] = pkh(lds[2 * kp][jr], lds[2 * kp + 1][jr]);
  }
}

// M[j][k] = sum_{q<90} W1[q][j] * W4[k][q] -> f16x2 rows (register-blocked, R11-proven).
extern "C" __global__ __launch_bounds__(256)
void m_kernel(const float* __restrict__ W1, const float* __restrict__ W4,
              uint32* __restrict__ MT) {
  const int j0 = (blockIdx.x >> 6) * 64, k0 = (blockIdx.x & 63) * 64;
  const int tid = threadIdx.x;
  __shared__ __align__(16) float aW[90][64];
  __shared__ __align__(16) float bT[90][64];
  for (int i = tid; i < 90 * 64; i += 256) {
    const int q = i >> 6, jl = i & 63;
    aW[q][jl] = W1[(size_t)q * Hn + j0 + jl];
  }
  for (int i = tid; i < 90 * 64; i += 256) {
    const int q = i >> 6, kl = i & 63;
    bT[q][kl] = W4[(size_t)(k0 + kl) * DYn + q];
  }
  __syncthreads();
  const int ty = tid >> 4, tx = tid & 15;
  float acc[4][4] = {};
#pragma unroll 2
  for (int q = 0; q < DYn; ++q) {
    const float4 av = *(const float4*)&aW[q][ty * 4];
    const float4 bv = *(const float4*)&bT[q][tx * 4];
    const float ar[4] = {av.x, av.y, av.z, av.w};
    const float br[4] = {bv.x, bv.y, bv.z, bv.w};
#pragma unroll
    for (int r = 0; r < 4; ++r)
#pragma unroll
      for (int c = 0; c < 4; ++c) acc[r][c] = fmaf(ar[r], br[c], acc[r][c]);
  }
#pragma unroll
  for (int r = 0; r < 4; ++r) {
    const size_t row = (size_t)(j0 + ty * 4 + r) * 2048 + (k0 >> 1) + tx * 2;
#pragma unroll
    for (int c = 0; c < 2; ++c)
      MT[row + c] = pkh(acc[r][2 * c], acc[r][2 * c + 1]);
  }
}

// c[j] = sum_{q<90} b4[q] * W1[q][j]  (f32)
extern "C" __global__ __launch_bounds__(256)
void c_kernel(const float* __restrict__ W1, const float* __restrict__ b4,
              float* __restrict__ c) {
  const int j = blockIdx.x * 256 + threadIdx.x;
  float a = 0.f;
#pragma unroll 6
  for (int q = 0; q < DYn; ++q) a = fmaf(b4[q], W1[(size_t)q * Hn + j], a);
  c[j] = a;
}

// UP[t][j] = b1[j] + u_t . W1[90:170][j], f16x2-packed.
extern "C" __global__ __launch_bounds__(512)
void up_kernel(const float* __restrict__ J, const float* __restrict__ W1,
               const float* __restrict__ b1, uint32* __restrict__ UPb) {
  const int t = blockIdx.x >> 3, jc = blockIdx.x & 7;
  const int j = jc * 512 + threadIdx.x;
  __shared__ float us[DPn];
  __shared__ float oa[512];
  if (threadIdx.x < DPn) us[threadIdx.x] = J[(size_t)t * DINn + DYn + threadIdx.x];
  __syncthreads();
  float acc = b1[j];
#pragma unroll 8
  for (int k = 0; k < DPn; ++k) acc = fmaf(us[k], W1[(size_t)(DYn + k) * Hn + j], acc);
  oa[threadIdx.x] = acc;
  __syncthreads();
  if (threadIdx.x < 256)
    UPb[(size_t)t * 2048 + jc * 256 + threadIdx.x] = pkh(oa[2 * threadIdx.x], oa[2 * threadIdx.x + 1]);
}

// ---------------- scan ----------------
__device__ __forceinline__ float dot_lds(const uint32* __restrict__ Wrow,
                                         const uint32* __restrict__ hvp, int l) {
  float a = 0.f;
#pragma unroll
  for (int i = 0; i < 8; ++i) {
    const uint4 u = *(const uint4*)&Wrow[i * 256 + l * 4];
    const uint4 h = *(const uint4*)&hvp[i * 256 + l * 4];
    a = dot2(h.x, u.x, a); a = dot2(h.y, u.y, a);
    a = dot2(h.z, u.z, a); a = dot2(h.w, u.w, a);
  }
  return wred(a);
}

__device__ __forceinline__ float dot_pf(const uint4* pf, const uint32* __restrict__ hvp, int l) {
  float a = 0.f;
#pragma unroll
  for (int i = 0; i < 8; ++i) {
    const uint4 h = *(const uint4*)&hvp[i * 256 + l * 4];
    const uint4 u = pf[i];
    a = dot2(h.x, u.x, a); a = dot2(h.y, u.y, a);
    a = dot2(h.z, u.z, a); a = dot2(h.w, u.w, a);
  }
  return wred(a);
}

// Pull one tagged exchange (2048 u64) via ONE 16B device-scope load/thread + retries.
__device__ __forceinline__ void pull16(const uint64* __restrict__ X, uint32* __restrict__ hvp,
                                       uint32 tag, int tid) {
  const uint64* p = X + 2 * tid;
  uint4 v = ld16_dev(p);
  unsigned spins = 0;
  while (v.y != tag || v.w != tag) {
    __builtin_amdgcn_s_sleep(1);
    v = ld16_dev(p);
    if (++spins > (1u << 22)) break;
  }
  hvp[2 * tid] = v.x;
  hvp[2 * tid + 1] = v.z;
}

extern "C" __global__ __launch_bounds__(BLK, 1)
void scan9_kernel(const float* __restrict__ J, const float* __restrict__ b2,
                  const float* __restrict__ b3, const float* __restrict__ W1,
                  const float* __restrict__ W2, const uint32* __restrict__ W3T,
                  const uint32* __restrict__ MT, const uint32* __restrict__ UPb,
                  const float* __restrict__ cv,
                  uint64* __restrict__ H1X, uint64* __restrict__ H2X,
                  uint64* __restrict__ H3X, uint32* __restrict__ H3H) {
  const int bid = blockIdx.x, tid = threadIdx.x;
  const int w = tid >> 6, l = tid & 63;
  const int j0 = bid * 16, j = j0 + w;

  __shared__ __align__(16) uint32 W2L[16 * 2048];  // 16 W2 columns, f16x2 k-pairs
  __shared__ __align__(16) uint32 hvp[2048];
  __shared__ float h1s[16];
  __shared__ float ysA[96];

  // one-time stage: W2 columns j0..j0+15 from natural layout
  for (int kp = tid; kp < 2048; kp += BLK) {
    const float* r0 = W2 + (size_t)(2 * kp) * Hn + j0;
    const float* r1 = r0 + Hn;
#pragma unroll
    for (int q = 0; q < 4; ++q) {
      const float4 a4 = *(const float4*)(r0 + 4 * q);
      const float4 c4 = *(const float4*)(r1 + 4 * q);
      W2L[(4 * q + 0) * 2048 + kp] = pkh(a4.x, c4.x);
      W2L[(4 * q + 1) * 2048 + kp] = pkh(a4.y, c4.y);
      W2L[(4 * q + 2) * 2048 + kp] = pkh(a4.z, c4.z);
      W2L[(4 * q + 3) * 2048 + kp] = pkh(a4.w, c4.w);
    }
  }
  uint4 pf[8];
  __syncthreads();

  for (int t = 0; t < TSn; ++t) {
    // ---- phase A: h1 ----
    if (t == 0) {
      if (tid < DYn) ysA[tid] = J[tid];
      __syncthreads();
      float a = 0.f;
      if (l < DYn) a = ysA[l] * W1[(size_t)l * Hn + j];
      if (l + 64 < DYn) a = fmaf(ysA[l + 64], W1[(size_t)(l + 64) * Hn + j], a);
      a = wred(a);
      if (l == 0) {
        const uint32 uu = UPb[(j >> 1)];
        h1s[w] = fmaxf(((j & 1) ? hhi(uu) : hlo(uu)) + a, 0.f);
      }
    } else {
      pull16(H3X, hvp, (uint32)t, tid);  // h3 of step t-1 carries tag t
      __syncthreads();
      const float a = dot_pf(pf, hvp, l);  // pf = M row (issued in C of t-1)
      if (l == 0) {
        const uint32 uu = UPb[(size_t)t * 2048 + (j >> 1)];
        h1s[w] = fmaxf(((j & 1) ? hhi(uu) : hlo(uu)) + cv[j] + a, 0.f);
      }
    }
    __syncthreads();
    if (tid < 8) {
      const uint32 pk = pkh(h1s[2 * tid], h1s[2 * tid + 1]);
      st_tag(H1X + bid * 8 + tid, (uint64)pk | ((uint64)(t + 1) << 32));
    }

    // issue W3 row prefetch (hides under the H1 poll)
    {
      const uint4* wr = (const uint4*)W3T + (size_t)j * 512 + l;
#pragma unroll
      for (int i = 0; i < 8; ++i) pf[i] = wr[i * 64];
    }

    // ---- phase B: h2 from LDS-resident W2 ----
    pull16(H1X, hvp, (uint32)(t + 1), tid);
    __syncthreads();
    {
      const float a = dot_lds(&W2L[w * 2048], hvp, l);
      if (l == 0) h1s[w] = fmaxf(b2[j] + a, 0.f);
    }
    __syncthreads();
    if (tid < 8) {
      const uint32 pk = pkh(h1s[2 * tid], h1s[2 * tid + 1]);
      st_tag(H2X + bid * 8 + tid, (uint64)pk | ((uint64)(t + 1) << 32));
    }

    // ---- phase C: h3 from prefetched W3, publish tagged + history ----
    pull16(H2X, hvp, (uint32)(t + 1), tid);
    __syncthreads();
    {
      const float a = dot_pf(pf, hvp, l);
      if (l == 0) h1s[w] = fmaxf(b3[j] + a, 0.f);
    }
    __syncthreads();
    if (tid < 8) {
      const uint32 pk = pkh(h1s[2 * tid], h1s[2 * tid + 1]);
      st_tag(H3X + bid * 8 + tid, (uint64)pk | ((uint64)(t + 1) << 32));
      H3H[(size_t)t * 2048 + bid * 8 + tid] = pk;  // plain store for post pass
    }

    // issue M row prefetch for next step's phase A (hides under H3 poll)
    {
      const uint4* wr = (const uint4*)MT + (size_t)j * 512 + l;
#pragma unroll
      for (int i = 0; i < 8; ++i) pf[i] = wr[i * 64];
    }
  }
}

// ---------------- epilogue: reconstruct y_t from h3 history + objectives ----------------
extern "C" __global__ __launch_bounds__(1024)
void post2_kernel(const float* __restrict__ J, const float* __restrict__ Pp,
                  const float* __restrict__ UppY, const float* __restrict__ LowY,
                  const float* __restrict__ UppP, const float* __restrict__ LowP,
                  const float* __restrict__ W4, const float* __restrict__ b4,
                  const float* __restrict__ scY, const float* __restrict__ mnY,
                  const float* __restrict__ scP, const float* __restrict__ mnP,
                  const uint32* __restrict__ H3H, float* __restrict__ out) {
  const int t = blockIdx.x, tid = threadIdx.x;
  __shared__ float h3s[4096];
  __shared__ float ps[8][128];
  __shared__ float ysv[96];
  if (t > 0) {
    for (int i = tid; i < 2048; i += 1024) {
      const uint32 u = H3H[(size_t)(t - 1) * 2048 + i];
      h3s[2 * i] = hlo(u);
      h3s[2 * i + 1] = hhi(u);
    }
    __syncthreads();
    const int p = tid >> 7, d = tid & 127;
    if (d < DYn) {
      float a = 0.f;
      const float* wp = W4 + d;
      const int k0 = p * 512;
#pragma unroll 8
      for (int k = k0; k < k0 + 512; ++k) a = fmaf(h3s[k], wp[(size_t)k * DYn], a);
      ps[p][d] = a;
    }
    __syncthreads();
    if (tid < DYn) {
      float s = b4[tid];
#pragma unroll
      for (int p2 = 0; p2 < 8; ++p2) s += ps[p2][tid];
      ysv[tid] = s;
    }
  } else {
    if (tid < DYn) ysv[tid] = J[tid];
  }
  __syncthreads();
  if (tid < DPn) {
    const float ph = fmaf(J[(size_t)t * DINn + DYn + tid], scP[tid], mnP[tid]);
    out[O_P1 + t * DPn + tid] = ph * Pp[t * DPn + tid];
    out[O_PU + t * DPn + tid] = fmaxf(ph - UppP[t * DPn + tid], 0.f);
    out[O_PL + t * DPn + tid] = fmaxf(LowP[t * DPn + tid] - ph, 0.f);
  }
  if (tid < DYn) {
    const float yh = fmaf(ysv[tid], scY[tid], mnY[tid]);
    out[O_YU + t * DYn + tid] = fmaxf(yh - UppY[t * DYn + tid], 0.f);
    out[O_YL + t * DYn + tid] = fmaxf(LowY[t * DYn + tid] - yh, 0.f);
  }
}

extern "C" void kernel_launch(void* const* d_in, const int* in_sizes, int n_in,
                              void* d_out, int out_size, void* d_ws, size_t ws_size,
                              hipStream_t stream) {
  const float* J    = (const float*)d_in[0];
  const float* Pp   = (const float*)d_in[1];
  const float* UppY = (const float*)d_in[2];
  const float* LowY = (const float*)d_in[3];
  const float* UppP = (const float*)d_in[4];
  const float* LowP = (const float*)d_in[5];
  const float* W1   = (const float*)d_in[6];
  const float* b1   = (const float*)d_in[7];
  const float* W2   = (const float*)d_in[8];
  const float* b2   = (const float*)d_in[9];
  const float* W3   = (const float*)d_in[10];
  const float* b3   = (const float*)d_in[11];
  const float* W4   = (const float*)d_in[12];
  const float* b4   = (const float*)d_in[13];
  const float* scY  = (const float*)d_in[14];
  const float* mnY  = (const float*)d_in[15];
  const float* scP  = (const float*)d_in[16];
  const float* mnP  = (const float*)d_in[17];
  float* out = (float*)d_out;

  if (ws_size < WS_NEED) return;

  char* base = (char*)d_ws;
  uint32* W3T = (uint32*)(base + B_W3T);
  uint32* MT  = (uint32*)(base + B_MT);
  uint32* UPb = (uint32*)(base + B_UPB);
  float*  cv  = (float*)(base + B_C);
  uint64* H1X = (uint64*)(base + B_H1X);
  uint64* H2X = (uint64*)(base + B_H2X);
  uint64* H3X = (uint64*)(base + B_H3X);
  uint32* H3H = (uint32*)(base + B_H3H);

  t3_kernel<<<dim3(4096), dim3(256), 0, stream>>>(W3, W3T);
  m_kernel<<<dim3(4096), dim3(256), 0, stream>>>(W1, W4, MT);
  c_kernel<<<dim3(16), dim3(256), 0, stream>>>(W1, b4, cv);
  up_kernel<<<dim3(TSn * 8), dim3(512), 0, stream>>>(J, W1, b1, UPb);
  scan9_kernel<<<dim3(NB), dim3(BLK), 0, stream>>>(
      J, b2, b3, W1, W2, W3T, MT, UPb, cv, H1X, H2X, H3X, H3H);
  post2_kernel<<<dim3(96), dim3(1024), 0, stream>>>(
      J, Pp, UppY, LowY, UppP, LowP, W4, b4, scY, mnY, scP, mnP, H3H, out);
}

// Round 14
// 817.906 us; speedup vs baseline: 1.8008x; 1.8008x over previous
//
#include <hip/hip_runtime.h>

#define NB 256
#define BLK 1024
#define TSn 95
#define DYn 90
#define DPn 80
#define DINn 170
#define Hn 4096

typedef unsigned int uint32;
typedef unsigned long long uint64;
typedef _Float16 h2v __attribute__((ext_vector_type(2)));

// ---- ws byte offsets (layout identical to R10-R13, payloads f16x2) ----
#define B_W3T 0ull             // 4096x4096 f16 transposed rows (8KB/row)
#define B_MT  33554432ull      // M = (W1a^T W4^T), same layout
#define B_UPB 67108864ull      // 95 x 2048 u32 (f16x2)
#define B_C   67887104ull      // 4096 f32
#define B_H1X 67903488ull      // uint64[2048] tagged {f16x2 payload, epoch}
#define B_H2X 67919872ull
#define B_H3X 67936256ull
#define B_H3H 67952640ull      // 95 x 2048 u32 (plain f16x2 h3 history)
#define WS_NEED 68730880ull

// out float offsets
#define O_YU 0
#define O_YL 8640
#define O_P1 17280
#define O_PU 24960
#define O_PL 32640

__device__ __forceinline__ void st_tag(uint64* p, uint64 v) {
  __hip_atomic_store(p, v, __ATOMIC_RELAXED, __HIP_MEMORY_SCOPE_AGENT);
}
__device__ __forceinline__ uint64 ld_tag(const uint64* p) {
  return __hip_atomic_load(p, __ATOMIC_RELAXED, __HIP_MEMORY_SCOPE_AGENT);
}
__device__ __forceinline__ uint32 pkh(float x, float y) {
  h2v h; h[0] = (_Float16)x; h[1] = (_Float16)y;
  return __builtin_bit_cast(uint32, h);
}
__device__ __forceinline__ float hlo(uint32 u) { h2v h = __builtin_bit_cast(h2v, u); return (float)h[0]; }
__device__ __forceinline__ float hhi(uint32 u) { h2v h = __builtin_bit_cast(h2v, u); return (float)h[1]; }
__device__ __forceinline__ float dot2(uint32 a, uint32 b, float c) {
  return __builtin_amdgcn_fdot2(__builtin_bit_cast(h2v, a), __builtin_bit_cast(h2v, b), c, false);
}
__device__ __forceinline__ float wred(float v) {
#pragma unroll
  for (int o = 32; o > 0; o >>= 1) v += __shfl_xor(v, o, 64);
  return v;
}

// ---------------- prologue kernels ----------------
// W3 f32 -> f16x2 transposed rows.
extern "C" __global__ __launch_bounds__(256)
void t3_kernel(const float* __restrict__ W3, uint32* __restrict__ W3T) {
  const int m = blockIdx.x;
  const int j0 = (m >> 6) * 64, k0 = (m & 63) * 64;
  const int t = threadIdx.x;
  __shared__ float lds[64][65];
  const int jl = t & 63, kb = t >> 6;
#pragma unroll
  for (int i = 0; i < 16; ++i) {
    const int kl = kb + 4 * i;
    lds[kl][jl] = W3[(size_t)(k0 + kl) * Hn + j0 + jl];
  }
  __syncthreads();
  const int kp = t & 31, jb = t >> 5;
#pragma unroll
  for (int i = 0; i < 8; ++i) {
    const int jr = jb + 8 * i;
    W3T[(size_t)(j0 + jr) * 2048 + (k0 >> 1) + kp] = pkh(lds[2 * kp][jr], lds[2 * kp + 1][jr]);
  }
}

// M[j][k] = sum_{q<90} W1[q][j] * W4[k][q] -> f16x2 rows (register-blocked, R11-proven).
extern "C" __global__ __launch_bounds__(256)
void m_kernel(const float* __restrict__ W1, const float* __restrict__ W4,
              uint32* __restrict__ MT) {
  const int j0 = (blockIdx.x >> 6) * 64, k0 = (blockIdx.x & 63) * 64;
  const int tid = threadIdx.x;
  __shared__ __align__(16) float aW[90][64];
  __shared__ __align__(16) float bT[90][64];
  for (int i = tid; i < 90 * 64; i += 256) {
    const int q = i >> 6, jl = i & 63;
    aW[q][jl] = W1[(size_t)q * Hn + j0 + jl];
  }
  for (int i = tid; i < 90 * 64; i += 256) {
    const int q = i >> 6, kl = i & 63;
    bT[q][kl] = W4[(size_t)(k0 + kl) * DYn + q];
  }
  __syncthreads();
  const int ty = tid >> 4, tx = tid & 15;
  float acc[4][4] = {};
#pragma unroll 2
  for (int q = 0; q < DYn; ++q) {
    const float4 av = *(const float4*)&aW[q][ty * 4];
    const float4 bv = *(const float4*)&bT[q][tx * 4];
    const float ar[4] = {av.x, av.y, av.z, av.w};
    const float br[4] = {bv.x, bv.y, bv.z, bv.w};
#pragma unroll
    for (int r = 0; r < 4; ++r)
#pragma unroll
      for (int c = 0; c < 4; ++c) acc[r][c] = fmaf(ar[r], br[c], acc[r][c]);
  }
#pragma unroll
  for (int r = 0; r < 4; ++r) {
    const size_t row = (size_t)(j0 + ty * 4 + r) * 2048 + (k0 >> 1) + tx * 2;
#pragma unroll
    for (int c = 0; c < 2; ++c)
      MT[row + c] = pkh(acc[r][2 * c], acc[r][2 * c + 1]);
  }
}

// c[j] = sum_{q<90} b4[q] * W1[q][j]  (f32)
extern "C" __global__ __launch_bounds__(256)
void c_kernel(const float* __restrict__ W1, const float* __restrict__ b4,
              float* __restrict__ c) {
  const int j = blockIdx.x * 256 + threadIdx.x;
  float a = 0.f;
#pragma unroll 6
  for (int q = 0; q < DYn; ++q) a = fmaf(b4[q], W1[(size_t)q * Hn + j], a);
  c[j] = a;
}

// UP[t][j] = b1[j] + u_t . W1[90:170][j], f16x2-packed.
extern "C" __global__ __launch_bounds__(512)
void up_kernel(const float* __restrict__ J, const float* __restrict__ W1,
               const float* __restrict__ b1, uint32* __restrict__ UPb) {
  const int t = blockIdx.x >> 3, jc = blockIdx.x & 7;
  const int j = jc * 512 + threadIdx.x;
  __shared__ float us[DPn];
  __shared__ float oa[512];
  if (threadIdx.x < DPn) us[threadIdx.x] = J[(size_t)t * DINn + DYn + threadIdx.x];
  __syncthreads();
  float acc = b1[j];
#pragma unroll 8
  for (int k = 0; k < DPn; ++k) acc = fmaf(us[k], W1[(size_t)(DYn + k) * Hn + j], acc);
  oa[threadIdx.x] = acc;
  __syncthreads();
  if (threadIdx.x < 256)
    UPb[(size_t)t * 2048 + jc * 256 + threadIdx.x] = pkh(oa[2 * threadIdx.x], oa[2 * threadIdx.x + 1]);
}

// ---------------- scan ----------------
__device__ __forceinline__ float dot_lds(const uint32* __restrict__ Wrow,
                                         const uint32* __restrict__ hvp, int l) {
  float a = 0.f;
#pragma unroll
  for (int i = 0; i < 8; ++i) {
    const uint4 u = *(const uint4*)&Wrow[i * 256 + l * 4];
    const uint4 h = *(const uint4*)&hvp[i * 256 + l * 4];
    a = dot2(h.x, u.x, a); a = dot2(h.y, u.y, a);
    a = dot2(h.z, u.z, a); a = dot2(h.w, u.w, a);
  }
  return wred(a);
}

__device__ __forceinline__ float dot_pf(const uint4* pf, const uint32* __restrict__ hvp, int l) {
  float a = 0.f;
#pragma unroll
  for (int i = 0; i < 8; ++i) {
    const uint4 h = *(const uint4*)&hvp[i * 256 + l * 4];
    const uint4 u = pf[i];
    a = dot2(h.x, u.x, a); a = dot2(h.y, u.y, a);
    a = dot2(h.z, u.z, a); a = dot2(h.w, u.w, a);
  }
  return wred(a);
}

// Pull one tagged exchange (2048 u64) into hvp[] LDS. R11-proven form:
// compiler-emitted relaxed agent atomic loads stay L2-CACHEABLE, so the 32
// blocks of an XCD share one L2 refill of the exchange (8 refills/hop, not
// 256). R12/R13's inline-asm sc-flag loads bypassed L2 -> 3.2 GB fill, +300us.
__device__ __forceinline__ void pull_h(const uint64* __restrict__ X, uint32* __restrict__ hvp,
                                       uint32 tag, int tid) {
  uint64 v0 = ld_tag(X + tid);
  uint64 v1 = ld_tag(X + tid + 1024);
  unsigned spins = 0;
  while ((uint32)(v0 >> 32) != tag || (uint32)(v1 >> 32) != tag) {
    __builtin_amdgcn_s_sleep(1);
    if ((uint32)(v0 >> 32) != tag) v0 = ld_tag(X + tid);
    if ((uint32)(v1 >> 32) != tag) v1 = ld_tag(X + tid + 1024);
    if (++spins > (1u << 22)) break;
  }
  hvp[tid] = (uint32)v0;
  hvp[tid + 1024] = (uint32)v1;
}

extern "C" __global__ __launch_bounds__(BLK, 1)
void scan10_kernel(const float* __restrict__ J, const float* __restrict__ b2,
                   const float* __restrict__ b3, const float* __restrict__ W1,
                   const float* __restrict__ W2, const uint32* __restrict__ W3T,
                   const uint32* __restrict__ MT, const uint32* __restrict__ UPb,
                   const float* __restrict__ cv,
                   uint64* __restrict__ H1X, uint64* __restrict__ H2X,
                   uint64* __restrict__ H3X, uint32* __restrict__ H3H) {
  const int bid = blockIdx.x, tid = threadIdx.x;
  const int w = tid >> 6, l = tid & 63;
  const int j0 = bid * 16, j = j0 + w;

  __shared__ __align__(16) uint32 W2L[16 * 2048];  // 16 W2 columns, f16x2 k-pairs
  __shared__ __align__(16) uint32 hvp[2048];
  __shared__ float h1s[16];
  __shared__ float ysA[96];

  // one-time stage: W2 columns j0..j0+15 from natural layout
  for (int kp = tid; kp < 2048; kp += BLK) {
    const float* r0 = W2 + (size_t)(2 * kp) * Hn + j0;
    const float* r1 = r0 + Hn;
#pragma unroll
    for (int q = 0; q < 4; ++q) {
      const float4 a4 = *(const float4*)(r0 + 4 * q);
      const float4 c4 = *(const float4*)(r1 + 4 * q);
      W2L[(4 * q + 0) * 2048 + kp] = pkh(a4.x, c4.x);
      W2L[(4 * q + 1) * 2048 + kp] = pkh(a4.y, c4.y);
      W2L[(4 * q + 2) * 2048 + kp] = pkh(a4.z, c4.z);
      W2L[(4 * q + 3) * 2048 + kp] = pkh(a4.w, c4.w);
    }
  }
  uint4 pf[8];
  __syncthreads();

  for (int t = 0; t < TSn; ++t) {
    // ---- phase A: h1 ----
    if (t == 0) {
      if (tid < DYn) ysA[tid] = J[tid];
      __syncthreads();
      float a = 0.f;
      if (l < DYn) a = ysA[l] * W1[(size_t)l * Hn + j];
      if (l + 64 < DYn) a = fmaf(ysA[l + 64], W1[(size_t)(l + 64) * Hn + j], a);
      a = wred(a);
      if (l == 0) {
        const uint32 uu = UPb[(j >> 1)];
        h1s[w] = fmaxf(((j & 1) ? hhi(uu) : hlo(uu)) + a, 0.f);
      }
    } else {
      pull_h(H3X, hvp, (uint32)t, tid);  // h3 of step t-1 carries tag t
      __syncthreads();
      const float a = dot_pf(pf, hvp, l);  // pf = M row (issued in C of t-1)
      if (l == 0) {
        const uint32 uu = UPb[(size_t)t * 2048 + (j >> 1)];
        h1s[w] = fmaxf(((j & 1) ? hhi(uu) : hlo(uu)) + cv[j] + a, 0.f);
      }
    }
    __syncthreads();
    if (tid < 8) {
      const uint32 pk = pkh(h1s[2 * tid], h1s[2 * tid + 1]);
      st_tag(H1X + bid * 8 + tid, (uint64)pk | ((uint64)(t + 1) << 32));
    }

    // issue W3 row prefetch (hides under the H1 poll)
    {
      const uint4* wr = (const uint4*)W3T + (size_t)j * 512 + l;
#pragma unroll
      for (int i = 0; i < 8; ++i) pf[i] = wr[i * 64];
    }

    // ---- phase B: h2 from LDS-resident W2 ----
    pull_h(H1X, hvp, (uint32)(t + 1), tid);
    __syncthreads();
    {
      const float a = dot_lds(&W2L[w * 2048], hvp, l);
      if (l == 0) h1s[w] = fmaxf(b2[j] + a, 0.f);
    }
    __syncthreads();
    if (tid < 8) {
      const uint32 pk = pkh(h1s[2 * tid], h1s[2 * tid + 1]);
      st_tag(H2X + bid * 8 + tid, (uint64)pk | ((uint64)(t + 1) << 32));
    }

    // ---- phase C: h3 from prefetched W3, publish tagged + history ----
    pull_h(H2X, hvp, (uint32)(t + 1), tid);
    __syncthreads();
    {
      const float a = dot_pf(pf, hvp, l);
      if (l == 0) h1s[w] = fmaxf(b3[j] + a, 0.f);
    }
    __syncthreads();
    if (tid < 8) {
      const uint32 pk = pkh(h1s[2 * tid], h1s[2 * tid + 1]);
      st_tag(H3X + bid * 8 + tid, (uint64)pk | ((uint64)(t + 1) << 32));
      H3H[(size_t)t * 2048 + bid * 8 + tid] = pk;  // plain store for post pass
    }

    // issue M row prefetch for next step's phase A (hides under H3 poll)
    {
      const uint4* wr = (const uint4*)MT + (size_t)j * 512 + l;
#pragma unroll
      for (int i = 0; i < 8; ++i) pf[i] = wr[i * 64];
    }
  }
}

// ---------------- epilogue: reconstruct y_t from h3 history + objectives ----------------
extern "C" __global__ __launch_bounds__(1024)
void post2_kernel(const float* __restrict__ J, const float* __restrict__ Pp,
                  const float* __restrict__ UppY, const float* __restrict__ LowY,
                  const float* __restrict__ UppP, const float* __restrict__ LowP,
                  const float* __restrict__ W4, const float* __restrict__ b4,
                  const float* __restrict__ scY, const float* __restrict__ mnY,
                  const float* __restrict__ scP, const float* __restrict__ mnP,
                  const uint32* __restrict__ H3H, float* __restrict__ out) {
  const int t = blockIdx.x, tid = threadIdx.x;
  __shared__ float h3s[4096];
  __shared__ float ps[8][128];
  __shared__ float ysv[96];
  if (t > 0) {
    for (int i = tid; i < 2048; i += 1024) {
      const uint32 u = H3H[(size_t)(t - 1) * 2048 + i];
      h3s[2 * i] = hlo(u);
      h3s[2 * i + 1] = hhi(u);
    }
    __syncthreads();
    const int p = tid >> 7, d = tid & 127;
    if (d < DYn) {
      float a = 0.f;
      const float* wp = W4 + d;
      const int k0 = p * 512;
#pragma unroll 8
      for (int k = k0; k < k0 + 512; ++k) a = fmaf(h3s[k], wp[(size_t)k * DYn], a);
      ps[p][d] = a;
    }
    __syncthreads();
    if (tid < DYn) {
      float s = b4[tid];
#pragma unroll
      for (int p2 = 0; p2 < 8; ++p2) s += ps[p2][tid];
      ysv[tid] = s;
    }
  } else {
    if (tid < DYn) ysv[tid] = J[tid];
  }
  __syncthreads();
  if (tid < DPn) {
    const float ph = fmaf(J[(size_t)t * DINn + DYn + tid], scP[tid], mnP[tid]);
    out[O_P1 + t * DPn + tid] = ph * Pp[t * DPn + tid];
    out[O_PU + t * DPn + tid] = fmaxf(ph - UppP[t * DPn + tid], 0.f);
    out[O_PL + t * DPn + tid] = fmaxf(LowP[t * DPn + tid] - ph, 0.f);
  }
  if (tid < DYn) {
    const float yh = fmaf(ysv[tid], scY[tid], mnY[tid]);
    out[O_YU + t * DYn + tid] = fmaxf(yh - UppY[t * DYn + tid], 0.f);
    out[O_YL + t * DYn + tid] = fmaxf(LowY[t * DYn + tid] - yh, 0.f);
  }
}

extern "C" void kernel_launch(void* const* d_in, const int* in_sizes, int n_in,
                              void* d_out, int out_size, void* d_ws, size_t ws_size,
                              hipStream_t stream) {
  const float* J    = (const float*)d_in[0];
  const float* Pp   = (const float*)d_in[1];
  const float* UppY = (const float*)d_in[2];
  const float* LowY = (const float*)d_in[3];
  const float* UppP = (const float*)d_in[4];
  const float* LowP = (const float*)d_in[5];
  const float* W1   = (const float*)d_in[6];
  const float* b1   = (const float*)d_in[7];
  const float* W2   = (const float*)d_in[8];
  const float* b2   = (const float*)d_in[9];
  const float* W3   = (const float*)d_in[10];
  const float* b3   = (const float*)d_in[11];
  const float* W4   = (const float*)d_in[12];
  const float* b4   = (const float*)d_in[13];
  const float* scY  = (const float*)d_in[14];
  const float* mnY  = (const float*)d_in[15];
  const float* scP  = (const float*)d_in[16];
  const float* mnP  = (const float*)d_in[17];
  float* out = (float*)d_out;

  if (ws_size < WS_NEED) return;

  char* base = (char*)d_ws;
  uint32* W3T = (uint32*)(base + B_W3T);
  uint32* MT  = (uint32*)(base + B_MT);
  uint32* UPb = (uint32*)(base + B_UPB);
  float*  cv  = (float*)(base + B_C);
  uint64* H1X = (uint64*)(base + B_H1X);
  uint64* H2X = (uint64*)(base + B_H2X);
  uint64* H3X = (uint64*)(base + B_H3X);
  uint32* H3H = (uint32*)(base + B_H3H);

  t3_kernel<<<dim3(4096), dim3(256), 0, stream>>>(W3, W3T);
  m_kernel<<<dim3(4096), dim3(256), 0, stream>>>(W1, W4, MT);
  c_kernel<<<dim3(16), dim3(256), 0, stream>>>(W1, b4, cv);
  up_kernel<<<dim3(TSn * 8), dim3(512), 0, stream>>>(J, W1, b1, UPb);
  scan10_kernel<<<dim3(NB), dim3(BLK), 0, stream>>>(
      J, b2, b3, W1, W2, W3T, MT, UPb, cv, H1X, H2X, H3X, H3H);
  post2_kernel<<<dim3(96), dim3(1024), 0, stream>>>(
      J, Pp, UppY, LowY, UppP, LowP, W4, b4, scY, mnY, scP, mnP, H3H, out);
}

// Round 15
// 811.503 us; speedup vs baseline: 1.8150x; 1.0079x over previous
//
#include <hip/hip_runtime.h>

#define NB 256
#define BLK 1024
#define TSn 95
#define DYn 90
#define DPn 80
#define DINn 170
#define Hn 4096

typedef unsigned int uint32;
typedef unsigned long long uint64;
typedef _Float16 h2v __attribute__((ext_vector_type(2)));

// ---- ws byte offsets ----
#define B_W3T 0ull             // 4096x4096 f16 transposed rows (8KB/row)
#define B_MT  33554432ull      // M = (W1a^T W4^T), same layout
#define B_UPB 67108864ull      // 95 x 2048 u32 (f16x2)
#define B_C   67887104ull      // 4096 f32
#define B_H1X 67903488ull      // uint64[2048] tagged {f16x2 payload, epoch}
#define B_H2X 67919872ull
#define B_H3X 67936256ull
#define B_H3H 67952640ull      // 95 x 2048 u32 (plain f16x2 h3 history)
#define B_W4T 68730880ull      // W4T2[i][d]: 2048 x 96 u32 (f16x2 over k-pairs)
#define WS_NEED 69517312ull    // <= 70721792 proven in R4

// out float offsets
#define O_YU 0
#define O_YL 8640
#define O_P1 17280
#define O_PU 24960
#define O_PL 32640

__device__ __forceinline__ void st_tag(uint64* p, uint64 v) {
  __hip_atomic_store(p, v, __ATOMIC_RELAXED, __HIP_MEMORY_SCOPE_AGENT);
}
__device__ __forceinline__ uint64 ld_tag(const uint64* p) {
  return __hip_atomic_load(p, __ATOMIC_RELAXED, __HIP_MEMORY_SCOPE_AGENT);
}
__device__ __forceinline__ uint32 pkh(float x, float y) {
  h2v h; h[0] = (_Float16)x; h[1] = (_Float16)y;
  return __builtin_bit_cast(uint32, h);
}
__device__ __forceinline__ float hlo(uint32 u) { h2v h = __builtin_bit_cast(h2v, u); return (float)h[0]; }
__device__ __forceinline__ float hhi(uint32 u) { h2v h = __builtin_bit_cast(h2v, u); return (float)h[1]; }
__device__ __forceinline__ float dot2(uint32 a, uint32 b, float c) {
  return __builtin_amdgcn_fdot2(__builtin_bit_cast(h2v, a), __builtin_bit_cast(h2v, b), c, false);
}
__device__ __forceinline__ float wred(float v) {
#pragma unroll
  for (int o = 32; o > 0; o >>= 1) v += __shfl_xor(v, o, 64);
  return v;
}

// ---------------- fused prologue: t3 | m | c | up | w4t in one dispatch ----------------
// grid = 4096 (W3 transpose) + 4096 (M gemm) + 16 (c) + 1520 (UP) + 192 (W4T2)
#define G_T3 4096
#define G_M  8192
#define G_C  8208
#define G_UP 9728
#define G_W4 9920

extern "C" __global__ __launch_bounds__(256)
void prep_kernel(const float* __restrict__ J, const float* __restrict__ W1,
                 const float* __restrict__ b1, const float* __restrict__ W3,
                 const float* __restrict__ W4, const float* __restrict__ b4,
                 uint32* __restrict__ W3T, uint32* __restrict__ MT,
                 float* __restrict__ cv, uint32* __restrict__ UPb,
                 uint32* __restrict__ W4T2) {
  const int b = blockIdx.x, tid = threadIdx.x;

  if (b < G_T3) {
    // ---- W3 f32 -> f16x2 transposed rows (R5-R14 proven body) ----
    const int j0 = (b >> 6) * 64, k0 = (b & 63) * 64;
    __shared__ float lds[64][65];
    const int jl = tid & 63, kb = tid >> 6;
#pragma unroll
    for (int i = 0; i < 16; ++i) {
      const int kl = kb + 4 * i;
      lds[kl][jl] = W3[(size_t)(k0 + kl) * Hn + j0 + jl];
    }
    __syncthreads();
    const int kp = tid & 31, jb = tid >> 5;
#pragma unroll
    for (int i = 0; i < 8; ++i) {
      const int jr = jb + 8 * i;
      W3T[(size_t)(j0 + jr) * 2048 + (k0 >> 1) + kp] = pkh(lds[2 * kp][jr], lds[2 * kp + 1][jr]);
    }
  } else if (b < G_M) {
    // ---- M[j][k] = sum_q W1[q][j]*W4[k][q] (register-blocked, R11-proven) ----
    const int mb = b - G_T3;
    const int j0 = (mb >> 6) * 64, k0 = (mb & 63) * 64;
    __shared__ __align__(16) float aW[90][64];
    __shared__ __align__(16) float bT[90][64];
    for (int i = tid; i < 90 * 64; i += 256) {
      const int q = i >> 6, jl = i & 63;
      aW[q][jl] = W1[(size_t)q * Hn + j0 + jl];
    }
    for (int i = tid; i < 90 * 64; i += 256) {
      const int q = i >> 6, kl = i & 63;
      bT[q][kl] = W4[(size_t)(k0 + kl) * DYn + q];
    }
    __syncthreads();
    const int ty = tid >> 4, tx = tid & 15;
    float acc[4][4] = {};
#pragma unroll 2
    for (int q = 0; q < DYn; ++q) {
      const float4 av = *(const float4*)&aW[q][ty * 4];
      const float4 bv = *(const float4*)&bT[q][tx * 4];
      const float ar[4] = {av.x, av.y, av.z, av.w};
      const float br[4] = {bv.x, bv.y, bv.z, bv.w};
#pragma unroll
      for (int r = 0; r < 4; ++r)
#pragma unroll
        for (int c = 0; c < 4; ++c) acc[r][c] = fmaf(ar[r], br[c], acc[r][c]);
    }
#pragma unroll
    for (int r = 0; r < 4; ++r) {
      const size_t row = (size_t)(j0 + ty * 4 + r) * 2048 + (k0 >> 1) + tx * 2;
#pragma unroll
      for (int c = 0; c < 2; ++c)
        MT[row + c] = pkh(acc[r][2 * c], acc[r][2 * c + 1]);
    }
  } else if (b < G_C) {
    // ---- c[j] = sum_q b4[q] * W1[q][j] ----
    const int j = (b - G_M) * 256 + tid;
    float a = 0.f;
#pragma unroll 6
    for (int q = 0; q < DYn; ++q) a = fmaf(b4[q], W1[(size_t)q * Hn + j], a);
    cv[j] = a;
  } else if (b < G_UP) {
    // ---- UP[t][j] = b1[j] + u_t . W1[90:170][j] (f16x2) ----
    const int bb = b - G_C;
    const int t = bb >> 4, jc = bb & 15;
    const int j = jc * 256 + tid;
    __shared__ float us[DPn];
    __shared__ float oa[256];
    if (tid < DPn) us[tid] = J[(size_t)t * DINn + DYn + tid];
    __syncthreads();
    float acc = b1[j];
#pragma unroll 8
    for (int k = 0; k < DPn; ++k) acc = fmaf(us[k], W1[(size_t)(DYn + k) * Hn + j], acc);
    oa[tid] = acc;
    __syncthreads();
    if (tid < 128)
      UPb[(size_t)t * 2048 + jc * 128 + tid] = pkh(oa[2 * tid], oa[2 * tid + 1]);
  } else {
    // ---- W4T2[i][d] = {W4[2i][d], W4[2i+1][d]} f16x2, d padded to 96 ----
    const int bb = b - G_UP;  // 0..191
    for (int k = 0; k < 4; ++k) {
      const int idx = (bb * 256 + tid) + k * 49152;  // < 196608
      const int i = idx / 96, d = idx - i * 96;
      float v0 = 0.f, v1 = 0.f;
      if (d < DYn) {
        v0 = W4[(size_t)(2 * i) * DYn + d];
        v1 = W4[(size_t)(2 * i + 1) * DYn + d];
      }
      W4T2[(size_t)i * 96 + d] = pkh(v0, v1);
    }
  }
}

// ---------------- scan (UNCHANGED from R14) ----------------
__device__ __forceinline__ float dot_lds(const uint32* __restrict__ Wrow,
                                         const uint32* __restrict__ hvp, int l) {
  float a = 0.f;
#pragma unroll
  for (int i = 0; i < 8; ++i) {
    const uint4 u = *(const uint4*)&Wrow[i * 256 + l * 4];
    const uint4 h = *(const uint4*)&hvp[i * 256 + l * 4];
    a = dot2(h.x, u.x, a); a = dot2(h.y, u.y, a);
    a = dot2(h.z, u.z, a); a = dot2(h.w, u.w, a);
  }
  return wred(a);
}

__device__ __forceinline__ float dot_pf(const uint4* pf, const uint32* __restrict__ hvp, int l) {
  float a = 0.f;
#pragma unroll
  for (int i = 0; i < 8; ++i) {
    const uint4 h = *(const uint4*)&hvp[i * 256 + l * 4];
    const uint4 u = pf[i];
    a = dot2(h.x, u.x, a); a = dot2(h.y, u.y, a);
    a = dot2(h.z, u.z, a); a = dot2(h.w, u.w, a);
  }
  return wred(a);
}

// Pull one tagged exchange (2048 u64) into hvp[] LDS. Compiler-emitted relaxed
// agent atomic loads stay L2-CACHEABLE -> 32 blocks/XCD share one refill.
__device__ __forceinline__ void pull_h(const uint64* __restrict__ X, uint32* __restrict__ hvp,
                                       uint32 tag, int tid) {
  uint64 v0 = ld_tag(X + tid);
  uint64 v1 = ld_tag(X + tid + 1024);
  unsigned spins = 0;
  while ((uint32)(v0 >> 32) != tag || (uint32)(v1 >> 32) != tag) {
    __builtin_amdgcn_s_sleep(1);
    if ((uint32)(v0 >> 32) != tag) v0 = ld_tag(X + tid);
    if ((uint32)(v1 >> 32) != tag) v1 = ld_tag(X + tid + 1024);
    if (++spins > (1u << 22)) break;
  }
  hvp[tid] = (uint32)v0;
  hvp[tid + 1024] = (uint32)v1;
}

extern "C" __global__ __launch_bounds__(BLK, 1)
void scan10_kernel(const float* __restrict__ J, const float* __restrict__ b2,
                   const float* __restrict__ b3, const float* __restrict__ W1,
                   const float* __restrict__ W2, const uint32* __restrict__ W3T,
                   const uint32* __restrict__ MT, const uint32* __restrict__ UPb,
                   const float* __restrict__ cv,
                   uint64* __restrict__ H1X, uint64* __restrict__ H2X,
                   uint64* __restrict__ H3X, uint32* __restrict__ H3H) {
  const int bid = blockIdx.x, tid = threadIdx.x;
  const int w = tid >> 6, l = tid & 63;
  const int j0 = bid * 16, j = j0 + w;

  __shared__ __align__(16) uint32 W2L[16 * 2048];  // 16 W2 columns, f16x2 k-pairs
  __shared__ __align__(16) uint32 hvp[2048];
  __shared__ float h1s[16];
  __shared__ float ysA[96];

  // one-time stage: W2 columns j0..j0+15 from natural layout
  for (int kp = tid; kp < 2048; kp += BLK) {
    const float* r0 = W2 + (size_t)(2 * kp) * Hn + j0;
    const float* r1 = r0 + Hn;
#pragma unroll
    for (int q = 0; q < 4; ++q) {
      const float4 a4 = *(const float4*)(r0 + 4 * q);
      const float4 c4 = *(const float4*)(r1 + 4 * q);
      W2L[(4 * q + 0) * 2048 + kp] = pkh(a4.x, c4.x);
      W2L[(4 * q + 1) * 2048 + kp] = pkh(a4.y, c4.y);
      W2L[(4 * q + 2) * 2048 + kp] = pkh(a4.z, c4.z);
      W2L[(4 * q + 3) * 2048 + kp] = pkh(a4.w, c4.w);
    }
  }
  uint4 pf[8];
  __syncthreads();

  for (int t = 0; t < TSn; ++t) {
    // ---- phase A: h1 ----
    if (t == 0) {
      if (tid < DYn) ysA[tid] = J[tid];
      __syncthreads();
      float a = 0.f;
      if (l < DYn) a = ysA[l] * W1[(size_t)l * Hn + j];
      if (l + 64 < DYn) a = fmaf(ysA[l + 64], W1[(size_t)(l + 64) * Hn + j], a);
      a = wred(a);
      if (l == 0) {
        const uint32 uu = UPb[(j >> 1)];
        h1s[w] = fmaxf(((j & 1) ? hhi(uu) : hlo(uu)) + a, 0.f);
      }
    } else {
      pull_h(H3X, hvp, (uint32)t, tid);  // h3 of step t-1 carries tag t
      __syncthreads();
      const float a = dot_pf(pf, hvp, l);  // pf = M row (issued in C of t-1)
      if (l == 0) {
        const uint32 uu = UPb[(size_t)t * 2048 + (j >> 1)];
        h1s[w] = fmaxf(((j & 1) ? hhi(uu) : hlo(uu)) + cv[j] + a, 0.f);
      }
    }
    __syncthreads();
    if (tid < 8) {
      const uint32 pk = pkh(h1s[2 * tid], h1s[2 * tid + 1]);
      st_tag(H1X + bid * 8 + tid, (uint64)pk | ((uint64)(t + 1) << 32));
    }

    // issue W3 row prefetch (hides under the H1 poll)
    {
      const uint4* wr = (const uint4*)W3T + (size_t)j * 512 + l;
#pragma unroll
      for (int i = 0; i < 8; ++i) pf[i] = wr[i * 64];
    }

    // ---- phase B: h2 from LDS-resident W2 ----
    pull_h(H1X, hvp, (uint32)(t + 1), tid);
    __syncthreads();
    {
      const float a = dot_lds(&W2L[w * 2048], hvp, l);
      if (l == 0) h1s[w] = fmaxf(b2[j] + a, 0.f);
    }
    __syncthreads();
    if (tid < 8) {
      const uint32 pk = pkh(h1s[2 * tid], h1s[2 * tid + 1]);
      st_tag(H2X + bid * 8 + tid, (uint64)pk | ((uint64)(t + 1) << 32));
    }

    // ---- phase C: h3 from prefetched W3, publish tagged + history ----
    pull_h(H2X, hvp, (uint32)(t + 1), tid);
    __syncthreads();
    {
      const float a = dot_pf(pf, hvp, l);
      if (l == 0) h1s[w] = fmaxf(b3[j] + a, 0.f);
    }
    __syncthreads();
    if (tid < 8) {
      const uint32 pk = pkh(h1s[2 * tid], h1s[2 * tid + 1]);
      st_tag(H3X + bid * 8 + tid, (uint64)pk | ((uint64)(t + 1) << 32));
      H3H[(size_t)t * 2048 + bid * 8 + tid] = pk;  // plain store for post pass
    }

    // issue M row prefetch for next step's phase A (hides under H3 poll)
    {
      const uint4* wr = (const uint4*)MT + (size_t)j * 512 + l;
#pragma unroll
      for (int i = 0; i < 8; ++i) pf[i] = wr[i * 64];
    }
  }
}

// ---------------- epilogue: y_t from h3 history via f16 W4T2 + objectives ----------------
extern "C" __global__ __launch_bounds__(1024)
void post3_kernel(const float* __restrict__ J, const float* __restrict__ Pp,
                  const float* __restrict__ UppY, const float* __restrict__ LowY,
                  const float* __restrict__ UppP, const float* __restrict__ LowP,
                  const uint32* __restrict__ W4T2, const float* __restrict__ b4,
                  const float* __restrict__ scY, const float* __restrict__ mnY,
                  const float* __restrict__ scP, const float* __restrict__ mnP,
                  const uint32* __restrict__ H3H, float* __restrict__ out) {
  const int t = blockIdx.x, tid = threadIdx.x;
  __shared__ uint32 h3p[2048];
  __shared__ float ps[8][128];
  __shared__ float ysv[96];
  if (t > 0) {
    for (int i = tid; i < 2048; i += 1024) h3p[i] = H3H[(size_t)(t - 1) * 2048 + i];
    __syncthreads();
    const int p = tid >> 7, d = tid & 127;
    if (d < 96) {
      float a = 0.f;
      const uint32* wr = W4T2 + (size_t)(p * 256) * 96 + d;
      const uint32* hp = h3p + p * 256;
#pragma unroll 8
      for (int i = 0; i < 256; ++i) a = dot2(hp[i], wr[(size_t)i * 96], a);
      ps[p][d] = a;
    }
    __syncthreads();
    if (tid < DYn) {
      float s = b4[tid];
#pragma unroll
      for (int p2 = 0; p2 < 8; ++p2) s += ps[p2][tid];
      ysv[tid] = s;
    }
  } else {
    if (tid < DYn) ysv[tid] = J[tid];
  }
  __syncthreads();
  if (tid < DPn) {
    const float ph = fmaf(J[(size_t)t * DINn + DYn + tid], scP[tid], mnP[tid]);
    out[O_P1 + t * DPn + tid] = ph * Pp[t * DPn + tid];
    out[O_PU + t * DPn + tid] = fmaxf(ph - UppP[t * DPn + tid], 0.f);
    out[O_PL + t * DPn + tid] = fmaxf(LowP[t * DPn + tid] - ph, 0.f);
  }
  if (tid < DYn) {
    const float yh = fmaf(ysv[tid], scY[tid], mnY[tid]);
    out[O_YU + t * DYn + tid] = fmaxf(yh - UppY[t * DYn + tid], 0.f);
    out[O_YL + t * DYn + tid] = fmaxf(LowY[t * DYn + tid] - yh, 0.f);
  }
}

extern "C" void kernel_launch(void* const* d_in, const int* in_sizes, int n_in,
                              void* d_out, int out_size, void* d_ws, size_t ws_size,
                              hipStream_t stream) {
  const float* J    = (const float*)d_in[0];
  const float* Pp   = (const float*)d_in[1];
  const float* UppY = (const float*)d_in[2];
  const float* LowY = (const float*)d_in[3];
  const float* UppP = (const float*)d_in[4];
  const float* LowP = (const float*)d_in[5];
  const float* W1   = (const float*)d_in[6];
  const float* b1   = (const float*)d_in[7];
  const float* W2   = (const float*)d_in[8];
  const float* b2   = (const float*)d_in[9];
  const float* W3   = (const float*)d_in[10];
  const float* b3   = (const float*)d_in[11];
  const float* W4   = (const float*)d_in[12];
  const float* b4   = (const float*)d_in[13];
  const float* scY  = (const float*)d_in[14];
  const float* mnY  = (const float*)d_in[15];
  const float* scP  = (const float*)d_in[16];
  const float* mnP  = (const float*)d_in[17];
  float* out = (float*)d_out;

  if (ws_size < WS_NEED) return;

  char* base = (char*)d_ws;
  uint32* W3T  = (uint32*)(base + B_W3T);
  uint32* MT   = (uint32*)(base + B_MT);
  uint32* UPb  = (uint32*)(base + B_UPB);
  float*  cv   = (float*)(base + B_C);
  uint64* H1X  = (uint64*)(base + B_H1X);
  uint64* H2X  = (uint64*)(base + B_H2X);
  uint64* H3X  = (uint64*)(base + B_H3X);
  uint32* H3H  = (uint32*)(base + B_H3H);
  uint32* W4T2 = (uint32*)(base + B_W4T);

  prep_kernel<<<dim3(G_W4), dim3(256), 0, stream>>>(
      J, W1, b1, W3, W4, b4, W3T, MT, cv, UPb, W4T2);
  scan10_kernel<<<dim3(NB), dim3(BLK), 0, stream>>>(
      J, b2, b3, W1, W2, W3T, MT, UPb, cv, H1X, H2X, H3X, H3H);
  post3_kernel<<<dim3(96), dim3(1024), 0, stream>>>(
      J, Pp, UppY, LowY, UppP, LowP, W4T2, b4, scY, mnY, scP, mnP, H3H, out);
}